// Round 2
// baseline (748.731 us; speedup 1.0000x reference)
//
#include <hip/hip_runtime.h>

// AvgPool2d k=3 s=2 VALID. x: (8,64,512,512) fp32 -> out: (8,64,255,255) fp32.
//
// All-dense-load / shuffle-neighbor / rolling-accumulator design:
//  - Lane i loads float4 at cols 4i and 256+4i (byte 16*i stride across the
//    wave) -> every global_load_dwordx4 is 100% cache-line dense; one wave
//    covers a full 512-col input row in exactly 2 load instructions.
//  - The window-overlap columns come from the NEIGHBOR LANE's registers via
//    __shfl(lane+1), not from memory: n0 = next lane's v0.x (col 4i+4),
//    n1 = next lane's v1.x (col 260+4i). Lane 63's n0 is exactly its
//    received n1 (col 256), so no scalar loads and no out-of-bounds reads.
//  - Horizontal 3-sums give out cols {2i, 2i+1, 128+2i, 129+2i} per lane ->
//    a full 255-col output row per wave.
//  - Vertical: rolling accumulator A = h(2m) over a band of BAND out rows;
//    each input row fetched exactly once per wave (33 rows per 32 unique).
//    2 output rows per loop iteration -> 8 dense dwordx4 loads batched.
//  - Output is write-once -> nontemporal stores.
//  - Grid: 512 planes x 4 blocks x 4 waves = 16 bands/plane, 2048 blocks.

#define IN_H 512
#define IN_W 512
#define OUT_H 255
#define OUT_W 255
#define PLANES 512   // N*C = 8*64
#define BAND 16      // output rows per wave (last band: 15)

__device__ __forceinline__ float4 ld4(const float* __restrict__ p) {
    return *(const float4*)p;
}

// Horizontal 3-sums for this lane's four output columns from one input row.
// v0 = cols 4i..4i+3, v1 = cols 256+4i..256+4i+3.
__device__ __forceinline__ float4 hsum(float4 v0, float4 v1, int nxt, bool is63) {
    float n0 = __shfl(v0.x, nxt);   // col 4(i+1)      (lane63: col 0 - fixed below)
    float n1 = __shfl(v1.x, nxt);   // col 256+4(i+1)  (lane63: col 256)
    if (is63) n0 = n1;              // lane63's out col 127 needs col 256 = its n1
    float4 h;
    h.x = v0.x + v0.y + v0.z;       // out 2i     : in 4i..4i+2
    h.y = v0.z + v0.w + n0;         // out 2i+1   : in 4i+2..4i+4
    h.z = v1.x + v1.y + v1.z;       // out 128+2i : in 256+4i..258+4i
    h.w = v1.z + v1.w + n1;         // out 129+2i : in 258+4i..260+4i (lane63: unused)
    return h;
}

__device__ __forceinline__ void st_row(float* __restrict__ op, float sx, float sy,
                                       float sz, float sw, bool not63) {
    const float inv9 = 1.0f / 9.0f;
    __builtin_nontemporal_store(sx * inv9, op);         // out col 2i
    __builtin_nontemporal_store(sy * inv9, op + 1);     // out col 2i+1
    __builtin_nontemporal_store(sz * inv9, op + 128);   // out col 128+2i
    if (not63)                                          // out col 255 doesn't exist
        __builtin_nontemporal_store(sw * inv9, op + 129);
}

__global__ __launch_bounds__(256) void KeyedAvgpool2d_kernel(
    const float* __restrict__ in, float* __restrict__ out) {
    const int lane = threadIdx.x & 63;
    const int wv   = threadIdx.x >> 6;
    const int band = blockIdx.x * 4 + wv;   // 0..15
    const int nc   = blockIdx.y;            // plane 0..511
    const int nxt  = (lane + 1) & 63;
    const bool is63 = (lane == 63);

    const int j0 = band * BAND;
    const int j1 = min(j0 + BAND, OUT_H);   // band 15 -> 15 rows
    const int nrows = j1 - j0;

    const float* __restrict__ rp =
        in + (size_t)nc * (IN_H * IN_W) + (size_t)(2 * j0) * IN_W + 4 * lane;
    float* __restrict__ op =
        out + (size_t)nc * (OUT_H * OUT_W) + (size_t)j0 * OUT_W + 2 * lane;

    // A = h(2*j0)
    float4 A;
    {
        float4 v0 = ld4(rp), v1 = ld4(rp + 256);
        A = hsum(v0, v1, nxt, is63);
    }

    const int npair = nrows >> 1;
#pragma unroll 2
    for (int it = 0; it < npair; ++it) {
        // Batch 8 dense loads: input rows 2m+1 .. 2m+4.
        const float* r1 = rp + IN_W;
        const float* r2 = rp + 2 * IN_W;
        const float* r3 = rp + 3 * IN_W;
        const float* r4 = rp + 4 * IN_W;
        float4 a1 = ld4(r1), b1 = ld4(r1 + 256);
        float4 a2 = ld4(r2), b2 = ld4(r2 + 256);
        float4 a3 = ld4(r3), b3 = ld4(r3 + 256);
        float4 a4 = ld4(r4), b4 = ld4(r4 + 256);
        rp += 4 * IN_W;

        float4 h1 = hsum(a1, b1, nxt, is63);
        float4 h2 = hsum(a2, b2, nxt, is63);
        float4 h3 = hsum(a3, b3, nxt, is63);
        float4 h4 = hsum(a4, b4, nxt, is63);

        // out row m   = A  + h1 + h2   (input rows 2m..2m+2)
        st_row(op, A.x + h1.x + h2.x, A.y + h1.y + h2.y,
                   A.z + h1.z + h2.z, A.w + h1.w + h2.w, !is63);
        // out row m+1 = h2 + h3 + h4   (input rows 2m+2..2m+4)
        st_row(op + OUT_W, h2.x + h3.x + h4.x, h2.y + h3.y + h4.y,
                           h2.z + h3.z + h4.z, h2.w + h3.w + h4.w, !is63);
        op += 2 * OUT_W;
        A = h4;                         // h(2(m+2))
    }

    if (nrows & 1) {                    // band 15: final out row 254
        const float* r1 = rp + IN_W;
        const float* r2 = rp + 2 * IN_W;    // input row 510 (max touched)
        float4 a1 = ld4(r1), b1 = ld4(r1 + 256);
        float4 a2 = ld4(r2), b2 = ld4(r2 + 256);
        float4 h1 = hsum(a1, b1, nxt, is63);
        float4 h2 = hsum(a2, b2, nxt, is63);
        st_row(op, A.x + h1.x + h2.x, A.y + h1.y + h2.y,
                   A.z + h1.z + h2.z, A.w + h1.w + h2.w, !is63);
    }
}

extern "C" void kernel_launch(void* const* d_in, const int* in_sizes, int n_in,
                              void* d_out, int out_size, void* d_ws, size_t ws_size,
                              hipStream_t stream) {
    const float* x = (const float*)d_in[0];
    float* o = (float*)d_out;

    dim3 block(256, 1, 1);          // 4 waves = 4 bands
    dim3 grid(4, PLANES, 1);        // 4*4 = 16 bands ; 512 planes
    KeyedAvgpool2d_kernel<<<grid, block, 0, stream>>>(x, o);
}